// Round 1
// baseline (706.390 us; speedup 1.0000x reference)
//
#include <hip/hip_runtime.h>

#define NCH 64
#define EPS 1e-5f

// ---------------- degree / dinv ----------------
__global__ void k_deg(const int* __restrict__ dst, int* __restrict__ deg, int E) {
    int e = blockIdx.x * blockDim.x + threadIdx.x;
    if (e < E) atomicAdd(&deg[dst[e]], 1);
}

__global__ void k_dinv(const int* __restrict__ deg, float* __restrict__ dinv, int N) {
    int i = blockIdx.x * blockDim.x + threadIdx.x;
    if (i < N) {
        int d = deg[i];
        dinv[i] = (d > 0) ? rsqrtf((float)d) : 0.0f;
    }
}

// ---------------- 3-kernel exclusive scan of deg -> rowstart ----------------
__global__ void k_scan1(const int* __restrict__ deg, int* __restrict__ bsum, int N) {
    __shared__ int s[256];
    int t = threadIdx.x;
    int i = blockIdx.x * 256 + t;
    s[t] = (i < N) ? deg[i] : 0;
    __syncthreads();
    for (int off = 128; off > 0; off >>= 1) {
        if (t < off) s[t] += s[t + off];
        __syncthreads();
    }
    if (t == 0) bsum[blockIdx.x] = s[0];
}

__global__ void k_scan2(int* __restrict__ bsum, int NB) {
    __shared__ int s[512];
    int t = threadIdx.x;
    int v = (t < NB) ? bsum[t] : 0;
    s[t] = v;
    __syncthreads();
    for (int off = 1; off < 512; off <<= 1) {
        int add = (t >= off) ? s[t - off] : 0;
        __syncthreads();
        s[t] += add;
        __syncthreads();
    }
    if (t < NB) bsum[t] = s[t] - v;  // exclusive
}

__global__ void k_scan3(const int* __restrict__ deg, const int* __restrict__ bsum,
                        int* __restrict__ rowstart, int N, int E) {
    __shared__ int s[256];
    int t = threadIdx.x;
    int i = blockIdx.x * 256 + t;
    int v = (i < N) ? deg[i] : 0;
    s[t] = v;
    __syncthreads();
    for (int off = 1; off < 256; off <<= 1) {
        int add = (t >= off) ? s[t - off] : 0;
        __syncthreads();
        s[t] += add;
        __syncthreads();
    }
    if (i < N) rowstart[i] = bsum[blockIdx.x] + (s[t] - v);
    if (i == N - 1) rowstart[N] = E;
}

// ---------------- CSR fill (packed {src, w}) ----------------
__global__ void k_fill(const int* __restrict__ src, const int* __restrict__ dst,
                       const float* __restrict__ dinv, const int* __restrict__ rowstart,
                       int* __restrict__ cursor, int2* __restrict__ csr, int E) {
    int e = blockIdx.x * blockDim.x + threadIdx.x;
    if (e >= E) return;
    int s = src[e], d = dst[e];
    float w = -dinv[s] * dinv[d];
    int pos = atomicAdd(&cursor[d], 1);
    csr[rowstart[d] + pos] = make_int2(s, __float_as_int(w));
}

// ---------------- propagation: y = prop(h)  (or 2*prop(h) - tx0) ----------------
// one wave per dst node, lane = channel
__global__ __launch_bounds__(256) void k_prop(const float* __restrict__ h,
                                              const int* __restrict__ rowstart,
                                              const int2* __restrict__ csr,
                                              const float* __restrict__ tx0,
                                              float* __restrict__ y, int N) {
    int gid = blockIdx.x * blockDim.x + threadIdx.x;
    int node = gid >> 6;
    int lane = gid & 63;
    if (node >= N) return;
    int e = rowstart[node];
    int s1 = rowstart[node + 1];
    float acc = 0.0f;
    for (; e + 4 <= s1; e += 4) {
        int2 c0 = csr[e], c1 = csr[e + 1], c2 = csr[e + 2], c3 = csr[e + 3];
        float h0 = h[c0.x * NCH + lane];
        float h1 = h[c1.x * NCH + lane];
        float h2 = h[c2.x * NCH + lane];
        float h3 = h[c3.x * NCH + lane];
        acc = fmaf(__int_as_float(c0.y), h0, acc);
        acc = fmaf(__int_as_float(c1.y), h1, acc);
        acc = fmaf(__int_as_float(c2.y), h2, acc);
        acc = fmaf(__int_as_float(c3.y), h3, acc);
    }
    for (; e < s1; e++) {
        int2 c = csr[e];
        acc = fmaf(__int_as_float(c.y), h[c.x * NCH + lane], acc);
    }
    float r = (tx0 != nullptr) ? (2.0f * acc - tx0[node * NCH + lane]) : acc;
    y[node * NCH + lane] = r;
}

// ---------------- dense combine: out = relu(Tx0@W[0]+Tx1@W[1]+Tx2@W[2]+b) ----------------
// one wave per 4 nodes; lane = output channel; W flattened [3*64][64]
__global__ __launch_bounds__(256) void k_dense(const float* __restrict__ tx0,
                                               const float* __restrict__ tx1,
                                               const float* __restrict__ tx2,
                                               const float* __restrict__ W,
                                               const float* __restrict__ b,
                                               float* __restrict__ out, int N) {
    __shared__ float sh[4][4][192];
    int t = threadIdx.x;
    int w = t >> 6;
    int lane = t & 63;
    int nodeBase = blockIdx.x * 16 + w * 4;
    for (int n = 0; n < 4; n++) {
        int node = nodeBase + n;
        if (node < N) {
            sh[w][n][lane]       = tx0[node * NCH + lane];
            sh[w][n][64 + lane]  = tx1[node * NCH + lane];
            sh[w][n][128 + lane] = tx2[node * NCH + lane];
        } else {
            sh[w][n][lane] = 0.0f;
            sh[w][n][64 + lane] = 0.0f;
            sh[w][n][128 + lane] = 0.0f;
        }
    }
    __syncthreads();
    float bb = b[lane];
    float acc0 = bb, acc1 = bb, acc2 = bb, acc3 = bb;
#pragma unroll 4
    for (int j = 0; j < 192; j += 4) {
        float4 t0 = *(const float4*)&sh[w][0][j];
        float4 t1 = *(const float4*)&sh[w][1][j];
        float4 t2 = *(const float4*)&sh[w][2][j];
        float4 t3 = *(const float4*)&sh[w][3][j];
        float w0 = W[(j + 0) * NCH + lane];
        float w1 = W[(j + 1) * NCH + lane];
        float w2 = W[(j + 2) * NCH + lane];
        float w3 = W[(j + 3) * NCH + lane];
        acc0 = fmaf(t0.x, w0, acc0); acc0 = fmaf(t0.y, w1, acc0);
        acc0 = fmaf(t0.z, w2, acc0); acc0 = fmaf(t0.w, w3, acc0);
        acc1 = fmaf(t1.x, w0, acc1); acc1 = fmaf(t1.y, w1, acc1);
        acc1 = fmaf(t1.z, w2, acc1); acc1 = fmaf(t1.w, w3, acc1);
        acc2 = fmaf(t2.x, w0, acc2); acc2 = fmaf(t2.y, w1, acc2);
        acc2 = fmaf(t2.z, w2, acc2); acc2 = fmaf(t2.w, w3, acc2);
        acc3 = fmaf(t3.x, w0, acc3); acc3 = fmaf(t3.y, w1, acc3);
        acc3 = fmaf(t3.z, w2, acc3); acc3 = fmaf(t3.w, w3, acc3);
    }
    acc0 = fmaxf(acc0, 0.0f);
    acc1 = fmaxf(acc1, 0.0f);
    acc2 = fmaxf(acc2, 0.0f);
    acc3 = fmaxf(acc3, 0.0f);
    if (nodeBase + 0 < N) out[(nodeBase + 0) * NCH + lane] = acc0;
    if (nodeBase + 1 < N) out[(nodeBase + 1) * NCH + lane] = acc1;
    if (nodeBase + 2 < N) out[(nodeBase + 2) * NCH + lane] = acc2;
    if (nodeBase + 3 < N) out[(nodeBase + 3) * NCH + lane] = acc3;
}

// ---------------- instance-norm stats (sum, sumsq per channel) ----------------
__global__ __launch_bounds__(256) void k_stats(const float* __restrict__ h,
                                               float* __restrict__ stats, int N) {
    int t = threadIdx.x;
    int lane = t & 63;
    int wv = t >> 6;
    int gw = blockIdx.x * 4 + wv;
    int nw = gridDim.x * 4;
    float s = 0.0f, q = 0.0f;
    for (int node = gw; node < N; node += nw) {
        float v = h[node * NCH + lane];
        s += v;
        q = fmaf(v, v, q);
    }
    __shared__ float sh[4][128];
    sh[wv][lane] = s;
    sh[wv][64 + lane] = q;
    __syncthreads();
    if (wv == 0) {
        float S = sh[0][lane] + sh[1][lane] + sh[2][lane] + sh[3][lane];
        float Q = sh[0][64 + lane] + sh[1][64 + lane] + sh[2][64 + lane] + sh[3][64 + lane];
        atomicAdd(&stats[lane], S);
        atomicAdd(&stats[64 + lane], Q);
    }
}

__global__ void k_final(float* __restrict__ stats, float invN) {
    int c = threadIdx.x;
    float m = stats[c] * invN;
    float q = stats[64 + c] * invN;
    float var = q - m * m;
    stats[128 + c] = m;
    stats[192 + c] = rsqrtf(var + EPS);
}

__global__ void k_norm(float* __restrict__ h, const float* __restrict__ stats, int total) {
    int i = blockIdx.x * blockDim.x + threadIdx.x;
    if (i >= total) return;
    int lane = i & 63;
    h[i] = (h[i] - stats[128 + lane]) * stats[192 + lane];
}

// ---------------- launcher ----------------
extern "C" void kernel_launch(void* const* d_in, const int* in_sizes, int n_in,
                              void* d_out, int out_size, void* d_ws, size_t ws_size,
                              hipStream_t stream) {
    const float* x  = (const float*)d_in[0];
    const int*   ei = (const int*)d_in[1];
    const float* W1 = (const float*)d_in[2];
    const float* b1 = (const float*)d_in[3];
    const float* W2 = (const float*)d_in[4];
    const float* b2 = (const float*)d_in[5];
    float* out = (float*)d_out;

    const int N = in_sizes[0] / NCH;
    const int E = in_sizes[1] / 2;
    const int* src = ei;
    const int* dst = ei + E;

    // workspace carve (256B aligned)
    char* p = (char*)d_ws;
    auto alloc = [&](size_t bytes) {
        void* r = (void*)p;
        p += ((bytes + 255) / 256) * 256;
        return r;
    };
    int*   deg      = (int*)alloc((size_t)N * 4);
    float* dinv     = (float*)alloc((size_t)N * 4);
    int*   rowstart = (int*)alloc((size_t)(N + 1) * 4);
    int*   cursor   = (int*)alloc((size_t)N * 4);
    const int NB1 = (N + 255) / 256;
    int*   bsum     = (int*)alloc((size_t)NB1 * 4);
    int2*  csr      = (int2*)alloc((size_t)E * 8);
    float* Tx1      = (float*)alloc((size_t)N * NCH * 4);
    float* Tx2      = (float*)alloc((size_t)N * NCH * 4);
    float* A        = (float*)alloc((size_t)N * NCH * 4);
    float* stats    = (float*)alloc(256 * 4);

    hipMemsetAsync(deg, 0, (size_t)N * 4, stream);
    hipMemsetAsync(cursor, 0, (size_t)N * 4, stream);

    const int TB = 256;
    // build CSR (by dst) + edge weights
    k_deg<<<(E + TB - 1) / TB, TB, 0, stream>>>(dst, deg, E);
    k_dinv<<<(N + TB - 1) / TB, TB, 0, stream>>>(deg, dinv, N);
    k_scan1<<<NB1, 256, 0, stream>>>(deg, bsum, N);
    k_scan2<<<1, 512, 0, stream>>>(bsum, NB1);
    k_scan3<<<NB1, 256, 0, stream>>>(deg, bsum, rowstart, N, E);
    k_fill<<<(E + TB - 1) / TB, TB, 0, stream>>>(src, dst, dinv, rowstart, cursor, csr, E);

    const int propBlocks = (N * NCH + TB - 1) / TB;
    const int denseBlocks = (N + 15) / 16;
    const int normBlocks = (N * NCH + TB - 1) / TB;
    const float invN = 1.0f / (float)N;

    // ---- layer 1 ----
    k_prop<<<propBlocks, TB, 0, stream>>>(x, rowstart, csr, nullptr, Tx1, N);
    k_prop<<<propBlocks, TB, 0, stream>>>(Tx1, rowstart, csr, x, Tx2, N);
    k_dense<<<denseBlocks, TB, 0, stream>>>(x, Tx1, Tx2, W1, b1, A, N);
    hipMemsetAsync(stats, 0, 128 * 4, stream);
    k_stats<<<512, TB, 0, stream>>>(A, stats, N);
    k_final<<<1, 64, 0, stream>>>(stats, invN);
    k_norm<<<normBlocks, TB, 0, stream>>>(A, stats, N * NCH);

    // ---- layer 2 ----
    k_prop<<<propBlocks, TB, 0, stream>>>(A, rowstart, csr, nullptr, Tx1, N);
    k_prop<<<propBlocks, TB, 0, stream>>>(Tx1, rowstart, csr, A, Tx2, N);
    k_dense<<<denseBlocks, TB, 0, stream>>>(A, Tx1, Tx2, W2, b2, out, N);
    hipMemsetAsync(stats, 0, 128 * 4, stream);
    k_stats<<<512, TB, 0, stream>>>(out, stats, N);
    k_final<<<1, 64, 0, stream>>>(stats, invN);
    k_norm<<<normBlocks, TB, 0, stream>>>(out, stats, N * NCH);
}